// Round 18
// baseline (411.015 us; speedup 1.0000x reference)
//
#include <hip/hip_runtime.h>
#include <hip/hip_bf16.h>

// ClassAtt fused pipeline — FINAL (R18 = R17, best measured: 410 µs).
// GEMMs at the characterized serial LDS+MFMA structural limit (~45% MfmaUtil,
// ~1045 TF): R2-exact 4-slot counted-vmcnt ring for G1/G2/G5, BK=64
// single-barrier for G4. Wave-per-row attn, single fused conversion launch.

typedef __bf16 bf16_t;
typedef __bf16 bf16x4 __attribute__((ext_vector_type(4)));
typedef __bf16 bf16x8 __attribute__((ext_vector_type(8)));
typedef float  f32x4  __attribute__((ext_vector_type(4)));

#define AS1(p) (const __attribute__((address_space(1))) void*)(p)
#define AS3(p) (__attribute__((address_space(3))) void*)(p)

// ---------------- ALL conversions in one launch ----------------
__global__ void cvt_all(const float* __restrict__ tube,
                        const float* __restrict__ w1, const float* __restrict__ w2,
                        const float* __restrict__ w3, const float* __restrict__ wh,
                        const float* __restrict__ wd1, const float* __restrict__ wd2,
                        const float* __restrict__ w1b, const float* __restrict__ w2b,
                        const float* __restrict__ w3b,
                        bf16_t* __restrict__ tubeB, bf16_t* __restrict__ w123,
                        bf16_t* __restrict__ whB, bf16_t* __restrict__ wd1B,
                        bf16_t* __restrict__ wd2B, float* __restrict__ bias123) {
  const int stride = gridDim.x * blockDim.x;
  for (int i = blockIdx.x * blockDim.x + threadIdx.x; i < 9044736; i += stride) {
    if (i >= 9043968) {                       // bias concat, f32 float4 copy
      int o = i - 9043968;
      const float* sb; int oo;
      if (o < 256)      { sb = w1b; oo = o; }
      else if (o < 512) { sb = w2b; oo = o - 256; }
      else              { sb = w3b; oo = o - 512; }
      ((float4*)bias123)[o] = ((const float4*)sb)[oo];
      continue;
    }
    const float* s; bf16_t* d; int o; int ns = 1 << 30;
    if (i < 6291456)      { s = tube; d = tubeB;          o = i; }
    else if (i < 6422528) { s = w1;  d = w123;            o = i - 6291456; }
    else if (i < 6553600) { s = w2;  d = w123 + 524288;   o = i - 6422528; }
    else if (i < 6684672) { s = w3;  d = w123 + 1048576;  o = i - 6553600; }
    else if (i < 7471104) { s = wh;  d = whB;             o = i - 6684672; }
    else if (i < 8519680) { s = wd1; d = wd1B;            o = i - 7471104; }
    else                  { s = wd2; d = wd2B;            o = i - 8519680; ns = 512000; }
    bf16x4 v;
    if (o < ns) {
      float4 f = ((const float4*)s)[o];
      v[0] = (bf16_t)f.x; v[1] = (bf16_t)f.y; v[2] = (bf16_t)f.z; v[3] = (bf16_t)f.w;
    } else {
      v[0] = (bf16_t)0.0f; v[1] = (bf16_t)0.0f; v[2] = (bf16_t)0.0f; v[3] = (bf16_t)0.0f;
    }
    *(bf16x4*)(d + (size_t)o * 4) = v;
  }
}

// ---------------- GEMM A: R2-exact (BK=32, 4-slot ring, counted vmcnt) ----------------
template<bool BDIAG, bool RELU, bool OUT_BF16>
__global__ __launch_bounds__(512, 2)
void gemm256(const bf16_t* __restrict__ A, int lda,
             const bf16_t* __restrict__ Bw, int ldb,
             const float* __restrict__ bias,
             void* __restrict__ Cout, int ldc,
             int K, int Nmask, int nbx)
{
  extern __shared__ char lds[];
  bf16_t* Ab = (bf16_t*)lds;
  bf16_t* Bb = (bf16_t*)(lds + 65536);

  const int t   = threadIdx.x;
  const int ln  = t & 63;
  const int w   = t >> 6;
  const int l15 = ln & 15, lhi = ln >> 4;
  const int wm  = w >> 2, wn = w & 3;

  const int nb = (int)gridDim.x;
  const int id = (int)blockIdx.x;
  const int id_sw = (id & 7) * (nb >> 3) + (id >> 3);
  const int bx = id_sw % nbx, by = id_sw / nbx;
  const int rowBase = by * 256;
  const int colBase = bx * 256;
  const int aCol0 = BDIAG ? (colBase >> 10) * 512 : 0;

  const int srow = (w << 4) + (ln >> 2);
  const int scol = (((ln & 3) ^ (ln >> 3)) & 3) << 3;

  const bf16_t* aS = A  + (size_t)(rowBase + srow) * lda + aCol0 + scol;
  const bf16_t* bS = Bw + (size_t)(colBase + srow) * ldb + scol;
  const size_t aI = (size_t)128 * lda;
  const size_t bI = (size_t)128 * ldb;
  bf16_t* daW = Ab + (w << 9);
  bf16_t* dbW = Bb + (w << 9);

  const int key  = (l15 >> 1) & 3;
  const int fcol = (lhi ^ key) << 3;
  const int aOff = (wm * 128 + l15) * 32 + fcol;
  const int bOff = (wn * 64  + l15) * 32 + fcol;

  const int nt = K >> 5;

  f32x4 acc[8][4] = {};

  #define STAGE(kt, s)                                                              \
    do {                                                                            \
      const bf16_t* a_ = aS + (size_t)(kt) * 32;                                    \
      const bf16_t* b_ = bS + (size_t)(kt) * 32;                                    \
      bf16_t* da_ = daW + (s) * 8192;                                               \
      bf16_t* db_ = dbW + (s) * 8192;                                               \
      __builtin_amdgcn_global_load_lds(AS1(a_),      AS3(da_),        16, 0, 0);    \
      __builtin_amdgcn_global_load_lds(AS1(a_ + aI), AS3(da_ + 4096), 16, 0, 0);    \
      __builtin_amdgcn_global_load_lds(AS1(b_),      AS3(db_),        16, 0, 0);    \
      __builtin_amdgcn_global_load_lds(AS1(b_ + bI), AS3(db_ + 4096), 16, 0, 0);    \
    } while (0)

  STAGE(0, 0); STAGE(1, 1); STAGE(2, 2);
  asm volatile("s_waitcnt vmcnt(8)" ::: "memory");
  __builtin_amdgcn_s_barrier();
  asm volatile("" ::: "memory");

  for (int j = 0; j < nt; ++j) {
    const int s = j & 3;
    const bf16_t* As_ = Ab + s * 8192 + aOff;
    const bf16_t* Bs_ = Bb + s * 8192 + bOff;

    bf16x8 af[8], bfr[4];
    #pragma unroll
    for (int mf = 0; mf < 8; ++mf) af[mf] = *(const bf16x8*)(As_ + mf * 512);
    #pragma unroll
    for (int nf = 0; nf < 4; ++nf) bfr[nf] = *(const bf16x8*)(Bs_ + nf * 512);

    if (j + 3 < nt) {
      STAGE(j + 3, ((j + 3) & 3));
      asm volatile("s_waitcnt vmcnt(8)" ::: "memory");
    } else if (j + 2 < nt) {
      asm volatile("s_waitcnt vmcnt(4)" ::: "memory");
    } else if (j + 1 < nt) {
      asm volatile("s_waitcnt vmcnt(0)" ::: "memory");
    }
    asm volatile("s_waitcnt lgkmcnt(0)" ::: "memory");
    __builtin_amdgcn_s_barrier();
    asm volatile("" ::: "memory");

    __builtin_amdgcn_s_setprio(1);
    #pragma unroll
    for (int mf = 0; mf < 8; ++mf)
      #pragma unroll
      for (int nf = 0; nf < 4; ++nf)
        acc[mf][nf] = __builtin_amdgcn_mfma_f32_16x16x32_bf16(af[mf], bfr[nf], acc[mf][nf], 0, 0, 0);
    __builtin_amdgcn_s_setprio(0);
  }
  #undef STAGE

  #pragma unroll
  for (int mf = 0; mf < 8; ++mf) {
    const int row = rowBase + wm * 128 + mf * 16 + lhi * 4;
    #pragma unroll
    for (int nf = 0; nf < 4; ++nf) {
      const int col = colBase + wn * 64 + nf * 16 + l15;
      const float bv = (col < Nmask) ? bias[col] : 0.0f;
      #pragma unroll
      for (int i = 0; i < 4; ++i) {
        float v = acc[mf][nf][i] + bv;
        if (RELU) v = fmaxf(v, 0.0f);
        if (OUT_BF16) {
          ((bf16_t*)Cout)[(size_t)(row + i) * ldc + col] = (bf16_t)v;
        } else {
          if (col < Nmask) ((float*)Cout)[(size_t)(row + i) * ldc + col] = v;
        }
      }
    }
  }
}

// ---------------- GEMM B: BK=64, 2-slot, single-barrier-per-tile (G4) --------
template<bool RELU, bool OUT_BF16>
__global__ __launch_bounds__(512, 2)
void gemm256k64(const bf16_t* __restrict__ A, int lda,
                const bf16_t* __restrict__ Bw, int ldb,
                const float* __restrict__ bias,
                void* __restrict__ Cout, int ldc,
                int K, int Nmask, int nbx)
{
  extern __shared__ char lds[];

  const int t   = threadIdx.x;
  const int ln  = t & 63;
  const int w   = t >> 6;
  const int l15 = ln & 15, lhi = ln >> 4;
  const int wm  = w >> 2, wn = w & 3;

  const int nb = (int)gridDim.x;
  const int id = (int)blockIdx.x;
  const int id_sw = (id & 7) * (nb >> 3) + (id >> 3);
  const int bx = id_sw % nbx, by = id_sw / nbx;
  const int rowBase = by * 256;
  const int colBase = bx * 256;

  const int srow = t >> 3;
  const int scol = (((t & 7) ^ (t >> 3)) & 7) << 3;
  const bf16_t* aS = A  + (size_t)(rowBase + srow) * lda + scol;
  const bf16_t* bS = Bw + (size_t)(colBase + srow) * ldb + scol;
  const size_t aI = (size_t)64 * lda;
  const size_t bI = (size_t)64 * ldb;
  char* daT = lds + t * 16;
  char* dbT = lds + 65536 + t * 16;

  const int rkey = l15 & 7;
  const int g0 = ((0 * 4 + lhi) ^ rkey) << 4;
  const int g1 = ((1 * 4 + lhi) ^ rkey) << 4;
  const int aRowB = (wm * 128 + l15) * 128;
  const int bRowB = (wn * 64  + l15) * 128;

  const int nt = K >> 6;

  f32x4 acc[8][4] = {};

  #define STG64(kt, s)                                                              \
    do {                                                                            \
      const bf16_t* a_ = aS + (size_t)(kt) * 64;                                    \
      const bf16_t* b_ = bS + (size_t)(kt) * 64;                                    \
      char* da_ = daT + (s) * 32768;                                                \
      char* db_ = dbT + (s) * 32768;                                                \
      _Pragma("unroll")                                                             \
      for (int i_ = 0; i_ < 4; ++i_) {                                              \
        __builtin_amdgcn_global_load_lds(AS1(a_ + i_ * aI), AS3(da_ + i_ * 8192), 16, 0, 0); \
        __builtin_amdgcn_global_load_lds(AS1(b_ + i_ * bI), AS3(db_ + i_ * 8192), 16, 0, 0); \
      }                                                                             \
    } while (0)

  #define RD64(s, G, AF, BF)                                                        \
    do {                                                                            \
      const char* pa_ = lds + (s) * 32768 + aRowB + (G);                            \
      const char* pb_ = lds + 65536 + (s) * 32768 + bRowB + (G);                    \
      _Pragma("unroll")                                                             \
      for (int mf_ = 0; mf_ < 8; ++mf_) AF[mf_] = *(const bf16x8*)(pa_ + mf_ * 2048);\
      _Pragma("unroll")                                                             \
      for (int nf_ = 0; nf_ < 4; ++nf_) BF[nf_] = *(const bf16x8*)(pb_ + nf_ * 2048);\
    } while (0)

  #define MM64(AF, BF)                                                              \
    do {                                                                            \
      __builtin_amdgcn_s_setprio(1);                                                \
      _Pragma("unroll")                                                             \
      for (int mf_ = 0; mf_ < 8; ++mf_)                                             \
        _Pragma("unroll")                                                           \
        for (int nf_ = 0; nf_ < 4; ++nf_)                                           \
          acc[mf_][nf_] = __builtin_amdgcn_mfma_f32_16x16x32_bf16(                  \
              AF[mf_], BF[nf_], acc[mf_][nf_], 0, 0, 0);                            \
      __builtin_amdgcn_s_setprio(0);                                                \
    } while (0)

  STG64(0, 0);
  asm volatile("s_waitcnt vmcnt(0)" ::: "memory");
  __builtin_amdgcn_s_barrier();
  asm volatile("" ::: "memory");

  for (int j = 0; j < nt; ++j) {
    const int s = j & 1;
    if (j + 1 < nt) STG64(j + 1, s ^ 1);

    bf16x8 af[8], bfr[4];
    RD64(s, g0, af, bfr);
    MM64(af, bfr);
    RD64(s, g1, af, bfr);
    MM64(af, bfr);

    if (j + 1 < nt) {
      asm volatile("s_waitcnt vmcnt(0)" ::: "memory");
      asm volatile("s_waitcnt lgkmcnt(0)" ::: "memory");
      __builtin_amdgcn_s_barrier();
      asm volatile("" ::: "memory");
    }
  }
  #undef STG64
  #undef RD64
  #undef MM64

  #pragma unroll
  for (int mf = 0; mf < 8; ++mf) {
    const int row = rowBase + wm * 128 + mf * 16 + lhi * 4;
    #pragma unroll
    for (int nf = 0; nf < 4; ++nf) {
      const int col = colBase + wn * 64 + nf * 16 + l15;
      const float bv = (col < Nmask) ? bias[col] : 0.0f;
      #pragma unroll
      for (int i = 0; i < 4; ++i) {
        float v = acc[mf][nf][i] + bv;
        if (RELU) v = fmaxf(v, 0.0f);
        if (OUT_BF16) {
          ((bf16_t*)Cout)[(size_t)(row + i) * ldc + col] = (bf16_t)v;
        } else {
          if (col < Nmask) ((float*)Cout)[(size_t)(row + i) * ldc + col] = v;
        }
      }
    }
  }
}

// ---------------- alphas -> softmax -> context: one wave per row ----------------
__global__ __launch_bounds__(256)
void attn_ctx(const bf16_t* __restrict__ P, bf16_t* __restrict__ ds) {
  const int w = threadIdx.x >> 6;
  const int l = threadIdx.x & 63;
  const int r = (blockIdx.x << 2) + w;
  const bf16_t* Prow = P + (size_t)r * 3072;
  bf16_t* dsrow = ds + (size_t)r * 2048;
  const int j = l << 4;

  bf16x8 lv0 = *(const bf16x8*)(dsrow + 1024 + j);
  bf16x8 lv1 = *(const bf16x8*)(dsrow + 1024 + j + 8);
  float lhf[16];
  #pragma unroll
  for (int q = 0; q < 8; ++q) { lhf[q] = (float)lv0[q]; lhf[8 + q] = (float)lv1[q]; }

  float pv[3][16];
  float s[3] = {0.f, 0.f, 0.f};
  #pragma unroll
  for (int e = 0; e < 3; ++e) {
    bf16x8 p0 = *(const bf16x8*)(Prow + e * 1024 + j);
    bf16x8 p1 = *(const bf16x8*)(Prow + e * 1024 + j + 8);
    #pragma unroll
    for (int q = 0; q < 8; ++q) { pv[e][q] = (float)p0[q]; pv[e][8 + q] = (float)p1[q]; }
    #pragma unroll
    for (int q = 0; q < 16; ++q) s[e] += lhf[q] * pv[e][q];
  }
  #pragma unroll
  for (int off = 1; off < 64; off <<= 1) {
    #pragma unroll
    for (int e = 0; e < 3; ++e) s[e] += __shfl_xor(s[e], off, 64);
  }
  const float mx = fmaxf(s[0], fmaxf(s[1], s[2]));
  const float e0 = expf(s[0] - mx), e1 = expf(s[1] - mx), e2 = expf(s[2] - mx);
  const float inv = 1.0f / (e0 + e1 + e2);
  const float w0 = e0 * inv, w1 = e1 * inv, w2 = e2 * inv;

  bf16x8 o0, o1;
  #pragma unroll
  for (int q = 0; q < 8; ++q) {
    o0[q] = (bf16_t)(w0 * pv[0][q]     + w1 * pv[1][q]     + w2 * pv[2][q]);
    o1[q] = (bf16_t)(w0 * pv[0][8 + q] + w1 * pv[1][8 + q] + w2 * pv[2][8 + q]);
  }
  *(bf16x8*)(dsrow + j)     = o0;
  *(bf16x8*)(dsrow + j + 8) = o1;
}

// ---------------- launch ----------------
extern "C" void kernel_launch(void* const* d_in, const int* in_sizes, int n_in,
                              void* d_out, int out_size, void* d_ws, size_t ws_size,
                              hipStream_t stream) {
  (void)in_sizes; (void)n_in; (void)out_size; (void)ws_size;

  const float* tube = (const float*)d_in[0];
  const float* w1W  = (const float*)d_in[1];
  const float* w1b  = (const float*)d_in[2];
  const float* w2W  = (const float*)d_in[3];
  const float* w2b  = (const float*)d_in[4];
  const float* w3W  = (const float*)d_in[5];
  const float* w3b  = (const float*)d_in[6];
  const float* whW  = (const float*)d_in[7];
  const float* whb  = (const float*)d_in[8];
  const float* wd1W = (const float*)d_in[9];
  const float* wd1b = (const float*)d_in[10];
  const float* wd2W = (const float*)d_in[11];
  const float* wd2b = (const float*)d_in[12];

  char* ws = (char*)d_ws;
  bf16_t* P       = (bf16_t*)(ws + 0);            // 16384x3072
  bf16_t* ds      = (bf16_t*)(ws + 100663296);    // 16384x2048
  bf16_t* wd1B    = (bf16_t*)(ws + 167772160);    // 2048x2048
  bf16_t* wd2B    = (bf16_t*)(ws + 176160768);    // 1024x2048 (rows 1000.. zero)
  bf16_t* whB     = (bf16_t*)(ws + 180355072);    // 1024x3072
  bf16_t* w123B   = (bf16_t*)(ws + 186646528);    // 3072x512
  bf16_t* tubeB   = (bf16_t*)(ws + 189792256);    // 16384x1536
  bf16_t* out1    = (bf16_t*)(ws + 180355072);    // 16384x2048, aliases whB..tubeB
  float*  bias123 = (float*)(ws + 247463936);     // 3072 f32

  hipFuncSetAttribute((const void*)(gemm256<true,  true,  true >),
                      hipFuncAttributeMaxDynamicSharedMemorySize, 131072);
  hipFuncSetAttribute((const void*)(gemm256<false, true,  true >),
                      hipFuncAttributeMaxDynamicSharedMemorySize, 131072);
  hipFuncSetAttribute((const void*)(gemm256<false, false, false>),
                      hipFuncAttributeMaxDynamicSharedMemorySize, 131072);
  hipFuncSetAttribute((const void*)(gemm256k64<true, true>),
                      hipFuncAttributeMaxDynamicSharedMemorySize, 131072);

  // ALL conversions in one launch (tube + weights + bias concat)
  hipLaunchKernelGGL(cvt_all, dim3(4096), dim3(256), 0, stream,
                     tube, w1W, w2W, w3W, whW, wd1W, wd2W, w1b, w2b, w3b,
                     tubeB, w123B, whB, wd1B, wd2B, bias123);

  // G1: P = relu(block-diag expert GEMM), N=3072, K=512  [R2-exact]
  hipLaunchKernelGGL((gemm256<true, true, true>), dim3(12 * 64), dim3(512), 131072, stream,
                     tubeB, 1536, w123B, 512, bias123, (void*)P, 3072, 512, 3072, 12);
  // G2: ds[:,1024:2048] = relu(P @ wh^T + b), N=1024, K=3072  [R2-exact]
  hipLaunchKernelGGL((gemm256<false, true, true>), dim3(4 * 64), dim3(512), 131072, stream,
                     P, 3072, whB, 3072, whb, (void*)(ds + 1024), 2048, 3072, 1024, 4);
  // attn: wave-per-row softmax/context
  hipLaunchKernelGGL(attn_ctx, dim3(4096), dim3(256), 0, stream, P, ds);
  // G4: out1 = relu(ds @ wd1^T + b), N=2048, K=2048  [BK=64 single-barrier]
  hipLaunchKernelGGL((gemm256k64<true, true>), dim3(8 * 64), dim3(512), 131072, stream,
                     ds, 2048, wd1B, 2048, wd1b, (void*)out1, 2048, 2048, 2048, 8);
  // G5: out = out1 @ wd2^T + b (fp32, N masked to 1000), K=2048  [R2-exact]
  hipLaunchKernelGGL((gemm256<false, false, false>), dim3(4 * 64), dim3(512), 131072, stream,
                     out1, 2048, wd2B, 2048, wd2b, d_out, 1000, 2048, 1000, 4);
}